// Round 9
// baseline (186.205 us; speedup 1.0000x reference)
//
#include <hip/hip_runtime.h>

#define SEQ   2048
#define BATCH 32
#define INF   256
#define NST   512
#define OUTF  256
#define CLEN  32
#define NCH   64
#define NJOB  4
#define NCG   (NCH / NJOB)          /* 16 chunk-groups of 128 timesteps */
#define NBLK  (NCG * BATCH)         /* 512 blocks */

typedef __bf16 bf16;
typedef __bf16 bf16x8 __attribute__((ext_vector_type(8)));
typedef float  f32x4  __attribute__((ext_vector_type(4)));

// ---------------------------------------------------------------------------
// K1: lambda = exp(-exp(ll)); lamG = lambda^128; B' = gamma*B (bf16); C (bf16)
// ---------------------------------------------------------------------------
__global__ void k_prep(const float* __restrict__ ll,
                       const float* __restrict__ Bm,
                       const float* __restrict__ Cm,
                       float* __restrict__ lam,
                       float* __restrict__ lamG,
                       bf16* __restrict__ Bb,
                       bf16* __restrict__ Cb) {
  int i = blockIdx.x * 256 + threadIdx.x;
  if (i < NST) {
    float lmb = expf(-expf(ll[i]));
    lam[i] = lmb;
    float p = lmb;
#pragma unroll
    for (int q = 0; q < 7; ++q) p *= p;   // lambda^128
    lamG[i] = p;
  }
  if (i < NST * INF) {
    int n = i >> 8;
    float lmb = expf(-expf(ll[n]));
    float g = sqrtf(1.0f - lmb * lmb + 1e-7f);
    Bb[i] = (bf16)(Bm[i] * g);
  }
  if (i < OUTF * NST) {
    Cb[i] = (bf16)(Cm[i]);
  }
}

// ---------------------------------------------------------------------------
// x staging helpers. LDS layout: [t][i] bf16, byte = (t*512+i*2) ^ ((t&15)<<4)
// NTH = threads in block (512 or 1024); each thread covers 2048/NTH slots.
// ---------------------------------------------------------------------------
template <int NTH>
__device__ __forceinline__ void xload(const float* __restrict__ xp, int tid,
                                      float4 xr[2048 / NTH]) {
#pragma unroll
  for (int rep = 0; rep < 2048 / NTH; ++rep) {
    int slot = rep * NTH + tid;
    int row = slot >> 6, col4 = slot & 63;
    xr[rep] = *(const float4*)(xp + (size_t)row * (BATCH * INF) + col4 * 4);
  }
}

template <int NTH>
__device__ __forceinline__ void xstore(char* xsb, int tid,
                                       const float4 xr[2048 / NTH]) {
#pragma unroll
  for (int rep = 0; rep < 2048 / NTH; ++rep) {
    int slot = rep * NTH + tid;
    int row = slot >> 6, col4 = slot & 63;
    union { bf16 h[4]; unsigned long long u; } pk;
    pk.h[0] = (bf16)xr[rep].x; pk.h[1] = (bf16)xr[rep].y;
    pk.h[2] = (bf16)xr[rep].z; pk.h[3] = (bf16)xr[rep].w;
    int byte = (row * (INF * 2) + col4 * 8) ^ ((row & 15) << 4);
    *(unsigned long long*)(xsb + byte) = pk.u;
  }
}

// ---------------------------------------------------------------------------
// in-register segmented scan over one chunk (32 t), NT n-fragments per wave.
// ---------------------------------------------------------------------------
template <int NT>
__device__ __forceinline__ void reg_scan(f32x4 acc[2][NT], float carry[NT],
                                         const float la[NT], const float l4[NT],
                                         int kg, int rl) {
#pragma unroll
  for (int mt = 0; mt < 2; ++mt) {
    float sl[NT][4];
#pragma unroll
    for (int nt = 0; nt < NT; ++nt) {
      sl[nt][0] = acc[mt][nt][0];
      sl[nt][1] = fmaf(la[nt], sl[nt][0], acc[mt][nt][1]);
      sl[nt][2] = fmaf(la[nt], sl[nt][1], acc[mt][nt][2]);
      sl[nt][3] = fmaf(la[nt], sl[nt][2], acc[mt][nt][3]);
    }
    float G[NT];
#pragma unroll
    for (int nt = 0; nt < NT; ++nt) {
      float g1 = __shfl_up(sl[nt][3], 16);
      G[nt] = (kg >= 1) ? fmaf(l4[nt], g1, sl[nt][3]) : sl[nt][3];
    }
#pragma unroll
    for (int nt = 0; nt < NT; ++nt) {
      float l8 = l4[nt] * l4[nt];
      float g2 = __shfl_up(G[nt], 32);
      G[nt] = (kg >= 2) ? fmaf(l8, g2, G[nt]) : G[nt];
    }
#pragma unroll
    for (int nt = 0; nt < NT; ++nt) {
      float X = __shfl_up(G[nt], 16);
      X = (kg >= 1) ? X : 0.0f;
      float l8 = l4[nt] * l4[nt];
      float p4k = ((kg & 1) ? l4[nt] : 1.0f) * ((kg & 2) ? l8 : 1.0f);
      float cin = fmaf(p4k, carry[nt], X);
      float l2 = la[nt] * la[nt], l3 = l2 * la[nt];
      acc[mt][nt][0] = fmaf(la[nt], cin, sl[nt][0]);
      acc[mt][nt][1] = fmaf(l2, cin, sl[nt][1]);
      acc[mt][nt][2] = fmaf(l3, cin, sl[nt][2]);
      acc[mt][nt][3] = fmaf(l4[nt], cin, sl[nt][3]);
    }
#pragma unroll
    for (int nt = 0; nt < NT; ++nt)
      carry[nt] = __shfl(acc[mt][nt][3], rl + 48);
  }
}

// ---------------------------------------------------------------------------
// GEMM1 with B' in registers (reads xs buffer); NT n-fragments per wave.
// ---------------------------------------------------------------------------
template <int NT>
__device__ __forceinline__ void gemm1_breg(const char* xsb,
                                           const bf16x8 Breg[8][NT],
                                           f32x4 acc[2][NT], int rl, int kg) {
#pragma unroll
  for (int k = 0; k < 8; ++k) {
    bf16x8 af[2];
#pragma unroll
    for (int mt = 0; mt < 2; ++mt) {
      int row = mt * 16 + rl;
      int byte = (row * (INF * 2) + (k * 32 + kg * 8) * 2) ^ (rl << 4);
      af[mt] = *(const bf16x8*)(xsb + byte);
    }
#pragma unroll
    for (int mt = 0; mt < 2; ++mt)
#pragma unroll
      for (int nt = 0; nt < NT; ++nt)
        acc[mt][nt] = __builtin_amdgcn_mfma_f32_16x16x32_bf16(af[mt], Breg[k][nt], acc[mt][nt], 0, 0, 0);
  }
}

// ---------------------------------------------------------------------------
// GEMM1 with B' streamed from L2 (low register pressure, fallback path)
// ---------------------------------------------------------------------------
__device__ __forceinline__ void gemm1_l2(const char* xsb, const bf16* __restrict__ Bb,
                                         f32x4 acc[2][4], int n0, int rl, int kg) {
#pragma unroll
  for (int k = 0; k < 8; ++k) {
    bf16x8 af[2], bfr[4];
#pragma unroll
    for (int mt = 0; mt < 2; ++mt) {
      int row = mt * 16 + rl;
      int byte = (row * (INF * 2) + (k * 32 + kg * 8) * 2) ^ (rl << 4);
      af[mt] = *(const bf16x8*)(xsb + byte);
    }
#pragma unroll
    for (int nt = 0; nt < 4; ++nt)
      bfr[nt] = *(const bf16x8*)(Bb + (size_t)(n0 + nt * 16 + rl) * INF + k * 32 + kg * 8);
#pragma unroll
    for (int mt = 0; mt < 2; ++mt)
#pragma unroll
      for (int nt = 0; nt < 4; ++nt)
        acc[mt][nt] = __builtin_amdgcn_mfma_f32_16x16x32_bf16(af[mt], bfr[nt], acc[mt][nt], 0, 0, 0);
  }
}

// ---------------------------------------------------------------------------
// PASS0: persistent block (b,cg); B' in regs; carry chained; writes Z. (R6-proven)
// ---------------------------------------------------------------------------
__global__ __launch_bounds__(512, 2)
void k_pass0(const float* __restrict__ x, const bf16* __restrict__ Bb,
             const float* __restrict__ lam, float* __restrict__ Z) {
  __shared__ __align__(16) char xs[2][CLEN * INF * 2];   // 2x16KB

  const int tid = threadIdx.x, wid = tid >> 6, lane = tid & 63;
  const int rl = lane & 15, kg = lane >> 4;
  const int b = blockIdx.x >> 4, cg = blockIdx.x & 15;
  const int n0 = wid * 64;

  float la[4], l4[4], carry[4];
#pragma unroll
  for (int nt = 0; nt < 4; ++nt) {
    float v = lam[n0 + nt * 16 + rl];
    la[nt] = v; l4[nt] = (v * v) * (v * v);
    carry[nt] = 0.0f;
  }

  bf16x8 Breg[8][4];
#pragma unroll
  for (int k = 0; k < 8; ++k)
#pragma unroll
    for (int nt = 0; nt < 4; ++nt)
      Breg[k][nt] = *(const bf16x8*)(Bb + (size_t)(n0 + nt * 16 + rl) * INF + k * 32 + kg * 8);

  {
    float4 xr0[4];
    xload<512>(x + ((size_t)(cg * NJOB * CLEN) * BATCH + b) * INF, tid, xr0);
    xstore<512>(xs[0], tid, xr0);
  }
  __syncthreads();

#pragma unroll
  for (int jj = 0; jj < NJOB; ++jj) {
    const int c = cg * NJOB + jj;
    f32x4 acc[2][4] = {};
    gemm1_breg<4>(&xs[jj & 1][0], Breg, acc, rl, kg);

    if (jj < NJOB - 1) {
      float4 xr[4];
      xload<512>(x + ((size_t)((c + 1) * CLEN) * BATCH + b) * INF, tid, xr);
      reg_scan<4>(acc, carry, la, l4, kg, rl);
      xstore<512>(xs[(jj + 1) & 1], tid, xr);
      __syncthreads();
    } else {
      reg_scan<4>(acc, carry, la, l4, kg, rl);
      if (kg == 0)
#pragma unroll
        for (int nt = 0; nt < 4; ++nt)
          Z[((size_t)cg * BATCH + b) * NST + n0 + nt * 16 + rl] = carry[nt];
    }
  }
}

// ---------------------------------------------------------------------------
// K3: exclusive prefix over chunk-groups: S0[g] = lamG*S0[g-1] + Z[g-1]
// ---------------------------------------------------------------------------
__global__ __launch_bounds__(128)
void k_chain(const float* __restrict__ Z, const float* __restrict__ lamG,
             float* __restrict__ S0) {
  const int b = blockIdx.x;
  const int n = blockIdx.y * 128 + threadIdx.x;
  const float lG = lamG[n];
  float z[NCG];
#pragma unroll
  for (int g = 0; g < NCG; ++g)
    z[g] = Z[((size_t)g * BATCH + b) * NST + n];
  float s = 0.0f;
#pragma unroll
  for (int g = 0; g < NCG; ++g) {
    S0[((size_t)g * BATCH + b) * NST + n] = s;
    s = fmaf(lG, s, z[g]);
  }
}

// ---------------------------------------------------------------------------
// STATES v2: 1024 threads / 16 waves, 32-n panel per wave -> Breg[8][2]=64 VGPR.
// GEMM1 pure LDS+MFMA (B' in regs), no spills (est ~122 VGPR <= 128 cap).
// Writes all states bf16 to St via ss de-swizzle. Row: [(s)*BATCH + b][n].
// ---------------------------------------------------------------------------
__global__ __launch_bounds__(1024, 4)
void k_states(const float* __restrict__ x, const bf16* __restrict__ Bb,
              const float* __restrict__ lam, const float* __restrict__ S0,
              bf16* __restrict__ St, float* __restrict__ fin) {
  __shared__ __align__(16) char xs[2][CLEN * INF * 2];   // 2x16KB
  __shared__ __align__(16) char ss[CLEN * NST * 2];      // 32KB

  const int tid = threadIdx.x, wid = tid >> 6, lane = tid & 63;
  const int rl = lane & 15, kg = lane >> 4;
  const int b = blockIdx.x >> 4, cg = blockIdx.x & 15;
  const int n0 = wid * 32;                                // 16 waves x 32 n

  float la[2], l4[2], carry[2];
#pragma unroll
  for (int nt = 0; nt < 2; ++nt) {
    float v = lam[n0 + nt * 16 + rl];
    la[nt] = v; l4[nt] = (v * v) * (v * v);
    carry[nt] = S0[((size_t)cg * BATCH + b) * NST + n0 + nt * 16 + rl];
  }

  bf16x8 Breg[8][2];
#pragma unroll
  for (int k = 0; k < 8; ++k)
#pragma unroll
    for (int nt = 0; nt < 2; ++nt)
      Breg[k][nt] = *(const bf16x8*)(Bb + (size_t)(n0 + nt * 16 + rl) * INF + k * 32 + kg * 8);

  {
    float4 xr0[2];
    xload<1024>(x + ((size_t)(cg * NJOB * CLEN) * BATCH + b) * INF, tid, xr0);
    xstore<1024>(xs[0], tid, xr0);
  }
  __syncthreads();

#pragma unroll
  for (int jj = 0; jj < NJOB; ++jj) {
    const int c = cg * NJOB + jj;
    const int lastj = (jj == NJOB - 1);

    f32x4 acc[2][2] = {};
    gemm1_breg<2>(&xs[jj & 1][0], Breg, acc, rl, kg);

    float4 xr[2];
    if (!lastj)
      xload<1024>(x + ((size_t)((c + 1) * CLEN) * BATCH + b) * INF, tid, xr);

    reg_scan<2>(acc, carry, la, l4, kg, rl);

    if (c == NCH - 1 && kg == 0)
#pragma unroll
      for (int nt = 0; nt < 2; ++nt)
        fin[(size_t)b * NST + n0 + nt * 16 + rl] = carry[nt];

    __syncthreads();   // A: all waves done with previous ss->global copy
#pragma unroll
    for (int mt = 0; mt < 2; ++mt)
#pragma unroll
      for (int nt = 0; nt < 2; ++nt)
#pragma unroll
        for (int r = 0; r < 4; ++r) {
          int t = mt * 16 + kg * 4 + r;
          int n = n0 + nt * 16 + rl;
          int byte = (t * (NST * 2) + n * 2) ^ ((t & 15) << 4);
          *(bf16*)(&ss[0] + byte) = (bf16)acc[mt][nt][r];
        }
    if (!lastj) xstore<1024>(xs[(jj + 1) & 1], tid, xr);
    __syncthreads();   // B: ss + next xs ready

    // ss -> St, de-swizzled, coalesced 16B stores; row = (c*32+t)*BATCH + b
#pragma unroll
    for (int q = 0; q < 2; ++q) {
      int slot = q * 1024 + tid;             // 0..2047 16B slots
      int t = slot >> 6, c16 = slot & 63;
      uint4 v = *(const uint4*)(&ss[0] + ((slot * 16) ^ ((t & 15) << 4)));
      size_t row = (size_t)(c * CLEN + t) * BATCH + b;
      *(uint4*)((char*)St + row * (NST * 2) + c16 * 16) = v;
    }
  }
}

// ---------------------------------------------------------------------------
// GEMM2: out[M=65536][O=256] = St[M][N=512] * C[O][N]^T.  128x128 tiles,
// 8 waves (2x4), BK=64, dbuf LDS reg-staged, XOR swizzle, XCD-pair swizzle.
// ---------------------------------------------------------------------------
__global__ __launch_bounds__(512, 2)
void k_gemm2(const bf16* __restrict__ St, const bf16* __restrict__ Cb,
             float* __restrict__ out) {
  __shared__ __align__(16) char As[2][128 * 64 * 2];   // 16KB each
  __shared__ __align__(16) char Bs[2][128 * 64 * 2];

  const int tid = threadIdx.x, wid = tid >> 6, lane = tid & 63;
  const int rl = lane & 15, kg = lane >> 4;
  // bijective XCD swizzle: consecutive work ids share an XCD (A-tile pairs)
  const int wk = (blockIdx.x & 7) * 128 + (blockIdx.x >> 3);
  const int m0 = (wk >> 1) * 128, nt0 = (wk & 1) * 128;
  const int wr = wid >> 2, wc = wid & 3;       // wave tile 64(M) x 32(N)

  const int s_row0 = tid >> 3, s_c16 = tid & 7;
  const int s_row1 = (tid + 512) >> 3;

#define LDA_BYTE(row, c16) (((row) * 128 + (c16) * 16) ^ (((row) & 7) << 4))

  uint4 ra0, ra1, rb0, rb1;
  ra0 = *(const uint4*)(St + (size_t)(m0 + s_row0) * NST + s_c16 * 8);
  ra1 = *(const uint4*)(St + (size_t)(m0 + s_row1) * NST + s_c16 * 8);
  rb0 = *(const uint4*)(Cb + (size_t)(nt0 + s_row0) * NST + s_c16 * 8);
  rb1 = *(const uint4*)(Cb + (size_t)(nt0 + s_row1) * NST + s_c16 * 8);
  *(uint4*)(&As[0][0] + LDA_BYTE(s_row0, s_c16)) = ra0;
  *(uint4*)(&As[0][0] + LDA_BYTE(s_row1, s_c16)) = ra1;
  *(uint4*)(&Bs[0][0] + LDA_BYTE(s_row0, s_c16)) = rb0;
  *(uint4*)(&Bs[0][0] + LDA_BYTE(s_row1, s_c16)) = rb1;
  __syncthreads();

  f32x4 acc[4][2] = {};
#pragma unroll
  for (int ks = 0; ks < 8; ++ks) {
    const int cur = ks & 1;
    if (ks < 7) {
      const int k0 = (ks + 1) * 64;
      ra0 = *(const uint4*)(St + (size_t)(m0 + s_row0) * NST + k0 + s_c16 * 8);
      ra1 = *(const uint4*)(St + (size_t)(m0 + s_row1) * NST + k0 + s_c16 * 8);
      rb0 = *(const uint4*)(Cb + (size_t)(nt0 + s_row0) * NST + k0 + s_c16 * 8);
      rb1 = *(const uint4*)(Cb + (size_t)(nt0 + s_row1) * NST + k0 + s_c16 * 8);
    }
#pragma unroll
    for (int ksub = 0; ksub < 2; ++ksub) {
      bf16x8 af[4], bfr[2];
#pragma unroll
      for (int mf = 0; mf < 4; ++mf) {
        int row = wr * 64 + mf * 16 + rl;
        af[mf] = *(const bf16x8*)(&As[cur][0] + (((row * 128) + ksub * 64 + kg * 16) ^ ((row & 7) << 4)));
      }
#pragma unroll
      for (int nf = 0; nf < 2; ++nf) {
        int row = wc * 32 + nf * 16 + rl;
        bfr[nf] = *(const bf16x8*)(&Bs[cur][0] + (((row * 128) + ksub * 64 + kg * 16) ^ ((row & 7) << 4)));
      }
#pragma unroll
      for (int mf = 0; mf < 4; ++mf)
#pragma unroll
        for (int nf = 0; nf < 2; ++nf)
          acc[mf][nf] = __builtin_amdgcn_mfma_f32_16x16x32_bf16(af[mf], bfr[nf], acc[mf][nf], 0, 0, 0);
    }
    if (ks < 7) {
      *(uint4*)(&As[cur ^ 1][0] + LDA_BYTE(s_row0, s_c16)) = ra0;
      *(uint4*)(&As[cur ^ 1][0] + LDA_BYTE(s_row1, s_c16)) = ra1;
      *(uint4*)(&Bs[cur ^ 1][0] + LDA_BYTE(s_row0, s_c16)) = rb0;
      *(uint4*)(&Bs[cur ^ 1][0] + LDA_BYTE(s_row1, s_c16)) = rb1;
    }
    __syncthreads();
  }
#undef LDA_BYTE

  // epilogue: C/D map col=lane&15, row=(lane>>4)*4+reg
#pragma unroll
  for (int mf = 0; mf < 4; ++mf)
#pragma unroll
    for (int nf = 0; nf < 2; ++nf)
#pragma unroll
      for (int r = 0; r < 4; ++r) {
        int m = m0 + wr * 64 + mf * 16 + kg * 4 + r;
        int o = nt0 + wc * 32 + nf * 16 + rl;
        out[(size_t)m * OUTF + o] = acc[mf][nf][r];
      }
}

// ---------------------------------------------------------------------------
// Fallback fused pass1 (R5-proven, 142us) when ws is too small for St.
// ---------------------------------------------------------------------------
__global__ __launch_bounds__(512)
void k_pass1_fb(const float* __restrict__ x, const bf16* __restrict__ Bb,
                const bf16* __restrict__ Cb, const float* __restrict__ lam,
                const float* __restrict__ S0, float* __restrict__ out,
                float* __restrict__ fin) {
  __shared__ __align__(16) char xs[2][CLEN * INF * 2];
  __shared__ __align__(16) char ss[CLEN * NST * 2];

  const int tid = threadIdx.x, wid = tid >> 6, lane = tid & 63;
  const int rl = lane & 15, kg = lane >> 4;
  const int b = blockIdx.x >> 4, cg = blockIdx.x & 15;
  const int n0 = wid * 64;

  float la[4], l4[4], carry[4];
#pragma unroll
  for (int nt = 0; nt < 4; ++nt) {
    float v = lam[n0 + nt * 16 + rl];
    la[nt] = v; l4[nt] = (v * v) * (v * v);
    carry[nt] = S0[((size_t)cg * BATCH + b) * NST + n0 + nt * 16 + rl];
  }
  {
    float4 xr0[4];
    xload<512>(x + ((size_t)(cg * NJOB * CLEN) * BATCH + b) * INF, tid, xr0);
    xstore<512>(xs[0], tid, xr0);
  }
  __syncthreads();

#pragma unroll
  for (int jj = 0; jj < NJOB; ++jj) {
    const int c = cg * NJOB + jj;
    f32x4 acc[2][4] = {};
    gemm1_l2(&xs[jj & 1][0], Bb, acc, n0, rl, kg);
    {
      float4 xr[4];
      const int lastj = (jj == NJOB - 1);
      if (!lastj)
        xload<512>(x + ((size_t)((c + 1) * CLEN) * BATCH + b) * INF, tid, xr);
      reg_scan<4>(acc, carry, la, l4, kg, rl);
      if (c == NCH - 1 && kg == 0)
#pragma unroll
        for (int nt = 0; nt < 4; ++nt)
          fin[(size_t)b * NST + n0 + nt * 16 + rl] = carry[nt];
      __syncthreads();
#pragma unroll
      for (int mt = 0; mt < 2; ++mt)
#pragma unroll
        for (int nt = 0; nt < 4; ++nt)
#pragma unroll
          for (int r = 0; r < 4; ++r) {
            int t = mt * 16 + kg * 4 + r;
            int n = n0 + nt * 16 + rl;
            int byte = (t * (NST * 2) + n * 2) ^ ((t & 15) << 4);
            *(bf16*)(&ss[0] + byte) = (bf16)acc[mt][nt][r];
          }
      if (!lastj) xstore<512>(xs[(jj + 1) & 1], tid, xr);
    }
    __syncthreads();

    const int o0 = wid * 32;
    f32x4 a2[2][2] = {};
#pragma unroll
    for (int k0 = 0; k0 < NST; k0 += 32) {
      bf16x8 af[2], cf[2];
#pragma unroll
      for (int mt = 0; mt < 2; ++mt) {
        int t = mt * 16 + rl;
        int byte = (t * (NST * 2) + (k0 + kg * 8) * 2) ^ (rl << 4);
        af[mt] = *(const bf16x8*)(&ss[0] + byte);
      }
#pragma unroll
      for (int ot = 0; ot < 2; ++ot)
        cf[ot] = *(const bf16x8*)(Cb + (size_t)(o0 + ot * 16 + rl) * NST + k0 + kg * 8);
#pragma unroll
      for (int mt = 0; mt < 2; ++mt)
#pragma unroll
        for (int ot = 0; ot < 2; ++ot)
          a2[mt][ot] = __builtin_amdgcn_mfma_f32_16x16x32_bf16(af[mt], cf[ot], a2[mt][ot], 0, 0, 0);
    }
#pragma unroll
    for (int mt = 0; mt < 2; ++mt)
#pragma unroll
      for (int ot = 0; ot < 2; ++ot)
#pragma unroll
        for (int r = 0; r < 4; ++r) {
          int t = mt * 16 + kg * 4 + r;
          int o = o0 + ot * 16 + rl;
          out[(((size_t)(c * CLEN + t)) * BATCH + b) * OUTF + o] = a2[mt][ot][r];
        }
  }
}

// ---------------------------------------------------------------------------
extern "C" void kernel_launch(void* const* d_in, const int* in_sizes, int n_in,
                              void* d_out, int out_size, void* d_ws, size_t ws_size,
                              hipStream_t stream) {
  const float* x  = (const float*)d_in[0];
  const float* ll = (const float*)d_in[1];
  const float* Bm = (const float*)d_in[2];
  const float* Cm = (const float*)d_in[3];

  char* ws = (char*)d_ws;
  float* lam  = (float*)(ws);
  float* lamG = (float*)(ws + 2048);
  bf16*  Bb   = (bf16*)(ws + 4096);
  bf16*  Cb   = (bf16*)(ws + 4096 + NST * INF * 2);
  float* Z    = (float*)(ws + 4096 + NST * INF * 2 + OUTF * NST * 2);
  float* S0   = (float*)((char*)Z + (size_t)NCG * BATCH * NST * 4);
  bf16*  St   = (bf16*)((char*)S0 + (size_t)NCG * BATCH * NST * 4);
  const size_t NEED = ((char*)St - ws) + (size_t)SEQ * BATCH * NST * 2;  // ~67MB

  float* out = (float*)d_out;
  float* fin = out + (size_t)SEQ * BATCH * OUTF;

  k_prep<<<dim3(512), dim3(256), 0, stream>>>(ll, Bm, Cm, lam, lamG, Bb, Cb);
  k_pass0<<<dim3(NBLK), dim3(512), 0, stream>>>(x, Bb, lam, Z);
  k_chain<<<dim3(BATCH, 4), dim3(128), 0, stream>>>(Z, lamG, S0);
  if (ws_size >= NEED) {
    k_states<<<dim3(NBLK), dim3(1024), 0, stream>>>(x, Bb, lam, S0, St, fin);
    k_gemm2<<<dim3(1024), dim3(512), 0, stream>>>(St, Cb, out);
  } else {
    k_pass1_fb<<<dim3(NBLK), dim3(512), 0, stream>>>(x, Bb, Cb, lam, S0, out, fin);
  }
}

// Round 10
// 98.768 us; speedup vs baseline: 1.8853x; 1.8853x over previous
//
#include <hip/hip_runtime.h>

#define SEQ   2048
#define BATCH 32
#define INF   256
#define NST   512
#define OUTF  256
#define CLEN  32
#define NCH   64
#define NJOB  4
#define NCG   (NCH / NJOB)          /* 16 chunk-groups of 128 timesteps */
#define NBLK  (NCG * BATCH)         /* 512 blocks */

typedef __bf16 bf16;
typedef __bf16 bf16x8 __attribute__((ext_vector_type(8)));
typedef float  f32x4  __attribute__((ext_vector_type(4)));

// ---------------------------------------------------------------------------
// K1: lam=exp(-exp(ll)); lamG=lam^128; l2la=log2(lam); B'=gamma*B bf16; C bf16
// ---------------------------------------------------------------------------
__global__ void k_prep(const float* __restrict__ ll,
                       const float* __restrict__ Bm,
                       const float* __restrict__ Cm,
                       float* __restrict__ lam,
                       float* __restrict__ lamG,
                       float* __restrict__ l2la,
                       bf16* __restrict__ Bb,
                       bf16* __restrict__ Cb) {
  int i = blockIdx.x * 256 + threadIdx.x;
  if (i < NST) {
    float e = expf(ll[i]);          // -ln(lambda)
    float lmb = expf(-e);
    lam[i] = lmb;
    l2la[i] = -e * 1.44269504088896341f;   // log2(lambda) = -e/ln2
    float p = lmb;
#pragma unroll
    for (int q = 0; q < 7; ++q) p *= p;    // lambda^128
    lamG[i] = p;
  }
  if (i < NST * INF) {
    int n = i >> 8;
    float lmb = expf(-expf(ll[n]));
    float g = sqrtf(1.0f - lmb * lmb + 1e-7f);
    Bb[i] = (bf16)(Bm[i] * g);
  }
  if (i < OUTF * NST) {
    Cb[i] = (bf16)(Cm[i]);
  }
}

// ---------------------------------------------------------------------------
// x staging helpers. LDS layout: [t][i] bf16, byte = (t*512+i*2) ^ ((t&15)<<4)
// ---------------------------------------------------------------------------
__device__ __forceinline__ void xload(const float* __restrict__ xp, int tid,
                                      float4 xr[4]) {
#pragma unroll
  for (int rep = 0; rep < 4; ++rep) {
    int slot = rep * 512 + tid;
    int row = slot >> 6, col4 = slot & 63;
    xr[rep] = *(const float4*)(xp + (size_t)row * (BATCH * INF) + col4 * 4);
  }
}

__device__ __forceinline__ void xstore(char* xsb, int tid, const float4 xr[4]) {
#pragma unroll
  for (int rep = 0; rep < 4; ++rep) {
    int slot = rep * 512 + tid;
    int row = slot >> 6, col4 = slot & 63;
    union { bf16 h[4]; unsigned long long u; } pk;
    pk.h[0] = (bf16)xr[rep].x; pk.h[1] = (bf16)xr[rep].y;
    pk.h[2] = (bf16)xr[rep].z; pk.h[3] = (bf16)xr[rep].w;
    int byte = (row * (INF * 2) + col4 * 8) ^ ((row & 15) << 4);
    *(unsigned long long*)(xsb + byte) = pk.u;
  }
}

// ---------------------------------------------------------------------------
// in-register segmented scan over one chunk (32 t). acc b->s in place.
// ---------------------------------------------------------------------------
__device__ __forceinline__ void reg_scan(f32x4 acc[2][4], float carry[4],
                                         const float la[4], const float l4[4],
                                         int kg, int rl) {
#pragma unroll
  for (int mt = 0; mt < 2; ++mt) {
    float sl[4][4];
#pragma unroll
    for (int nt = 0; nt < 4; ++nt) {
      sl[nt][0] = acc[mt][nt][0];
      sl[nt][1] = fmaf(la[nt], sl[nt][0], acc[mt][nt][1]);
      sl[nt][2] = fmaf(la[nt], sl[nt][1], acc[mt][nt][2]);
      sl[nt][3] = fmaf(la[nt], sl[nt][2], acc[mt][nt][3]);
    }
    float G[4];
#pragma unroll
    for (int nt = 0; nt < 4; ++nt) {
      float g1 = __shfl_up(sl[nt][3], 16);
      G[nt] = (kg >= 1) ? fmaf(l4[nt], g1, sl[nt][3]) : sl[nt][3];
    }
#pragma unroll
    for (int nt = 0; nt < 4; ++nt) {
      float l8 = l4[nt] * l4[nt];
      float g2 = __shfl_up(G[nt], 32);
      G[nt] = (kg >= 2) ? fmaf(l8, g2, G[nt]) : G[nt];
    }
#pragma unroll
    for (int nt = 0; nt < 4; ++nt) {
      float X = __shfl_up(G[nt], 16);
      X = (kg >= 1) ? X : 0.0f;
      float l8 = l4[nt] * l4[nt];
      float p4k = ((kg & 1) ? l4[nt] : 1.0f) * ((kg & 2) ? l8 : 1.0f);
      float cin = fmaf(p4k, carry[nt], X);
      float l2 = la[nt] * la[nt], l3 = l2 * la[nt];
      acc[mt][nt][0] = fmaf(la[nt], cin, sl[nt][0]);
      acc[mt][nt][1] = fmaf(l2, cin, sl[nt][1]);
      acc[mt][nt][2] = fmaf(l3, cin, sl[nt][2]);
      acc[mt][nt][3] = fmaf(l4[nt], cin, sl[nt][3]);
    }
#pragma unroll
    for (int nt = 0; nt < 4; ++nt)
      carry[nt] = __shfl(acc[mt][nt][3], rl + 48);
  }
}

// ---------------------------------------------------------------------------
// GEMM1 with B' in registers (reads xs buffer)
// ---------------------------------------------------------------------------
__device__ __forceinline__ void gemm1_breg(const char* xsb, const bf16x8 Breg[8][4],
                                           f32x4 acc[2][4], int rl, int kg) {
#pragma unroll
  for (int k = 0; k < 8; ++k) {
    bf16x8 af[2];
#pragma unroll
    for (int mt = 0; mt < 2; ++mt) {
      int row = mt * 16 + rl;
      int byte = (row * (INF * 2) + (k * 32 + kg * 8) * 2) ^ (rl << 4);
      af[mt] = *(const bf16x8*)(xsb + byte);
    }
#pragma unroll
    for (int mt = 0; mt < 2; ++mt)
#pragma unroll
      for (int nt = 0; nt < 4; ++nt)
        acc[mt][nt] = __builtin_amdgcn_mfma_f32_16x16x32_bf16(af[mt], Breg[k][nt], acc[mt][nt], 0, 0, 0);
  }
}

// ---------------------------------------------------------------------------
// GEMM1 with B' streamed from L2 (fallback path only)
// ---------------------------------------------------------------------------
__device__ __forceinline__ void gemm1_l2(const char* xsb, const bf16* __restrict__ Bb,
                                         f32x4 acc[2][4], int n0, int rl, int kg) {
#pragma unroll
  for (int k = 0; k < 8; ++k) {
    bf16x8 af[2], bfr[4];
#pragma unroll
    for (int mt = 0; mt < 2; ++mt) {
      int row = mt * 16 + rl;
      int byte = (row * (INF * 2) + (k * 32 + kg * 8) * 2) ^ (rl << 4);
      af[mt] = *(const bf16x8*)(xsb + byte);
    }
#pragma unroll
    for (int nt = 0; nt < 4; ++nt)
      bfr[nt] = *(const bf16x8*)(Bb + (size_t)(n0 + nt * 16 + rl) * INF + k * 32 + kg * 8);
#pragma unroll
    for (int mt = 0; mt < 2; ++mt)
#pragma unroll
      for (int nt = 0; nt < 4; ++nt)
        acc[mt][nt] = __builtin_amdgcn_mfma_f32_16x16x32_bf16(af[mt], bfr[nt], acc[mt][nt], 0, 0, 0);
  }
}

// ---------------------------------------------------------------------------
// PASS0<STORE>: persistent block (b,cg); B' in regs; carry chained from 0.
// Writes group-final Z. STORE=1: also writes local-scanned states (bf16) to
// bfrag[cg][b][dt=jj*32+t][n] (the group-carry fixup happens in k_gemm2b).
// ---------------------------------------------------------------------------
template <int STORE>
__global__ __launch_bounds__(512, 2)
void k_pass0(const float* __restrict__ x, const bf16* __restrict__ Bb,
             const float* __restrict__ lam, float* __restrict__ Z,
             bf16* __restrict__ bfrag) {
  __shared__ __align__(16) char xs[2][CLEN * INF * 2];   // 2x16KB

  const int tid = threadIdx.x, wid = tid >> 6, lane = tid & 63;
  const int rl = lane & 15, kg = lane >> 4;
  const int b = blockIdx.x >> 4, cg = blockIdx.x & 15;
  const int n0 = wid * 64;

  float la[4], l4[4], carry[4];
#pragma unroll
  for (int nt = 0; nt < 4; ++nt) {
    float v = lam[n0 + nt * 16 + rl];
    la[nt] = v; l4[nt] = (v * v) * (v * v);
    carry[nt] = 0.0f;
  }

  bf16x8 Breg[8][4];
#pragma unroll
  for (int k = 0; k < 8; ++k)
#pragma unroll
    for (int nt = 0; nt < 4; ++nt)
      Breg[k][nt] = *(const bf16x8*)(Bb + (size_t)(n0 + nt * 16 + rl) * INF + k * 32 + kg * 8);

  {
    float4 xr0[4];
    xload(x + ((size_t)(cg * NJOB * CLEN) * BATCH + b) * INF, tid, xr0);
    xstore(xs[0], tid, xr0);
  }
  __syncthreads();

#pragma unroll
  for (int jj = 0; jj < NJOB; ++jj) {
    const int c = cg * NJOB + jj;
    f32x4 acc[2][4] = {};
    gemm1_breg(&xs[jj & 1][0], Breg, acc, rl, kg);

    float4 xr[4];
    if (jj < NJOB - 1)
      xload(x + ((size_t)((c + 1) * CLEN) * BATCH + b) * INF, tid, xr);

    reg_scan(acc, carry, la, l4, kg, rl);

    if (STORE) {
      const size_t rowbase = ((size_t)cg * BATCH + b) * 128 + jj * 32;
#pragma unroll
      for (int mt = 0; mt < 2; ++mt)
#pragma unroll
        for (int nt = 0; nt < 4; ++nt)
#pragma unroll
          for (int r = 0; r < 4; ++r) {
            int t = mt * 16 + kg * 4 + r;
            int n = n0 + nt * 16 + rl;
            bfrag[(rowbase + t) * NST + n] = (bf16)acc[mt][nt][r];
          }
    }

    if (jj < NJOB - 1) {
      xstore(xs[(jj + 1) & 1], tid, xr);
      __syncthreads();
    } else {
      if (kg == 0)
#pragma unroll
        for (int nt = 0; nt < 4; ++nt)
          Z[((size_t)cg * BATCH + b) * NST + n0 + nt * 16 + rl] = carry[nt];
    }
  }
}

// ---------------------------------------------------------------------------
// K3: exclusive prefix over groups: S0[g] = lamG*S0[g-1] + Z[g-1]; writes fin.
// ---------------------------------------------------------------------------
__global__ __launch_bounds__(128)
void k_chain(const float* __restrict__ Z, const float* __restrict__ lamG,
             float* __restrict__ S0, float* __restrict__ fin) {
  const int b = blockIdx.x;
  const int n = blockIdx.y * 128 + threadIdx.x;
  const float lG = lamG[n];
  float z[NCG];
#pragma unroll
  for (int g = 0; g < NCG; ++g)
    z[g] = Z[((size_t)g * BATCH + b) * NST + n];
  float s = 0.0f;
#pragma unroll
  for (int g = 0; g < NCG; ++g) {
    S0[((size_t)g * BATCH + b) * NST + n] = s;
    s = fmaf(lG, s, z[g]);
  }
  fin[(size_t)b * NST + n] = s;
}

// ---------------------------------------------------------------------------
// GEMM2b: per block = (c2 0..31, b): 64 timestep-rows x 256 o.
// Stage bfrag tile -> LDS with fused carry fixup s = s0 + 2^((dt+1)*log2la)*S0g,
// ONE barrier, then barrier-free K-loop: A from swizzled LDS, C from L2.
// ---------------------------------------------------------------------------
__global__ __launch_bounds__(512)
void k_gemm2b(const bf16* __restrict__ bfrag, const bf16* __restrict__ Cb,
              const float* __restrict__ S0, const float* __restrict__ l2la,
              float* __restrict__ out) {
  __shared__ __align__(16) char ss[64 * NST * 2];   // 64 rows x 1KB, XOR swz

  const int tid = threadIdx.x, wid = tid >> 6, lane = tid & 63;
  const int rl = lane & 15, kg = lane >> 4;
  const int c2 = blockIdx.x >> 5, b = blockIdx.x & 31;
  const int cg = c2 >> 1;
  const int dtbase = (c2 & 1) * 64;

  // per-thread n-slice (same 8 n for all staged chunks)
  const int n8 = (tid & 63) * 8;
  float l2a[8], s0g[8];
#pragma unroll
  for (int j = 0; j < 8; ++j) {
    l2a[j] = l2la[n8 + j];
    s0g[j] = S0[((size_t)cg * BATCH + b) * NST + n8 + j];
  }

  // ---- stage 64x512 bf16 tile with fused fixup
  const uint4* src = (const uint4*)(bfrag +
      (((size_t)cg * BATCH + b) * 128 + dtbase) * NST);
#pragma unroll
  for (int q = 0; q < 8; ++q) {
    int chunk = q * 512 + tid;        // linear 16B chunks of the 64KB tile
    int tl = chunk >> 6;              // row 0..63
    union { uint4 u; bf16 h[8]; } in, ot;
    in.u = src[chunk];
    float dtp1 = (float)(dtbase + tl + 1);
#pragma unroll
    for (int j = 0; j < 8; ++j) {
      float s = fmaf(exp2f(dtp1 * l2a[j]), s0g[j], (float)in.h[j]);
      ot.h[j] = (bf16)s;
    }
    int byte = (tl * (NST * 2) + (chunk & 63) * 16) ^ ((tl & 15) << 4);
    *(uint4*)(&ss[0] + byte) = ot.u;
  }
  __syncthreads();

  // ---- K-loop: wave owns o-panel [wid*32, +32), all 64 rows
  const int o0 = wid * 32;
  f32x4 acc[4][2] = {};
#pragma unroll
  for (int kq = 0; kq < 16; ++kq) {
    const int k0 = kq * 32;
    bf16x8 af[4], cf[2];
#pragma unroll
    for (int mf = 0; mf < 4; ++mf) {
      int t = mf * 16 + rl;
      af[mf] = *(const bf16x8*)(&ss[0] +
          ((t * (NST * 2) + (k0 + kg * 8) * 2) ^ ((t & 15) << 4)));
    }
#pragma unroll
    for (int ot2 = 0; ot2 < 2; ++ot2)
      cf[ot2] = *(const bf16x8*)(Cb + (size_t)(o0 + ot2 * 16 + rl) * NST + k0 + kg * 8);
#pragma unroll
    for (int mf = 0; mf < 4; ++mf)
#pragma unroll
      for (int ot2 = 0; ot2 < 2; ++ot2)
        acc[mf][ot2] = __builtin_amdgcn_mfma_f32_16x16x32_bf16(af[mf], cf[ot2], acc[mf][ot2], 0, 0, 0);
  }

  // ---- epilogue: D row=(lane>>4)*4+reg (within 16), col=lane&15
#pragma unroll
  for (int mf = 0; mf < 4; ++mf)
#pragma unroll
    for (int ot2 = 0; ot2 < 2; ++ot2)
#pragma unroll
      for (int r = 0; r < 4; ++r) {
        int ml = mf * 16 + kg * 4 + r;             // row in tile
        size_t srow = (size_t)c2 * 64 + ml;        // global timestep index
        int o = o0 + ot2 * 16 + rl;
        out[(srow * BATCH + b) * OUTF + o] = acc[mf][ot2][r];
      }
}

// ---------------------------------------------------------------------------
// Fallback fused pass1 (R5-proven, ~142us) when ws is too small for bfrag.
// ---------------------------------------------------------------------------
__global__ __launch_bounds__(512)
void k_pass1_fb(const float* __restrict__ x, const bf16* __restrict__ Bb,
                const bf16* __restrict__ Cb, const float* __restrict__ lam,
                const float* __restrict__ S0, float* __restrict__ out,
                float* __restrict__ fin) {
  __shared__ __align__(16) char xs[2][CLEN * INF * 2];
  __shared__ __align__(16) char ss[CLEN * NST * 2];

  const int tid = threadIdx.x, wid = tid >> 6, lane = tid & 63;
  const int rl = lane & 15, kg = lane >> 4;
  const int b = blockIdx.x >> 4, cg = blockIdx.x & 15;
  const int n0 = wid * 64;

  float la[4], l4[4], carry[4];
#pragma unroll
  for (int nt = 0; nt < 4; ++nt) {
    float v = lam[n0 + nt * 16 + rl];
    la[nt] = v; l4[nt] = (v * v) * (v * v);
    carry[nt] = S0[((size_t)cg * BATCH + b) * NST + n0 + nt * 16 + rl];
  }
  {
    float4 xr0[4];
    xload(x + ((size_t)(cg * NJOB * CLEN) * BATCH + b) * INF, tid, xr0);
    xstore(xs[0], tid, xr0);
  }
  __syncthreads();

#pragma unroll
  for (int jj = 0; jj < NJOB; ++jj) {
    const int c = cg * NJOB + jj;
    f32x4 acc[2][4] = {};
    gemm1_l2(&xs[jj & 1][0], Bb, acc, n0, rl, kg);
    {
      float4 xr[4];
      const int lastj = (jj == NJOB - 1);
      if (!lastj)
        xload(x + ((size_t)((c + 1) * CLEN) * BATCH + b) * INF, tid, xr);
      reg_scan(acc, carry, la, l4, kg, rl);
      if (c == NCH - 1 && kg == 0)
#pragma unroll
        for (int nt = 0; nt < 4; ++nt)
          fin[(size_t)b * NST + n0 + nt * 16 + rl] = carry[nt];
      __syncthreads();
#pragma unroll
      for (int mt = 0; mt < 2; ++mt)
#pragma unroll
        for (int nt = 0; nt < 4; ++nt)
#pragma unroll
          for (int r = 0; r < 4; ++r) {
            int t = mt * 16 + kg * 4 + r;
            int n = n0 + nt * 16 + rl;
            int byte = (t * (NST * 2) + n * 2) ^ ((t & 15) << 4);
            *(bf16*)(&ss[0] + byte) = (bf16)acc[mt][nt][r];
          }
      if (!lastj) xstore(xs[(jj + 1) & 1], tid, xr);
    }
    __syncthreads();

    const int o0 = wid * 32;
    f32x4 a2[2][2] = {};
#pragma unroll
    for (int k0 = 0; k0 < NST; k0 += 32) {
      bf16x8 af[2], cf[2];
#pragma unroll
      for (int mt = 0; mt < 2; ++mt) {
        int t = mt * 16 + rl;
        int byte = (t * (NST * 2) + (k0 + kg * 8) * 2) ^ (rl << 4);
        af[mt] = *(const bf16x8*)(&ss[0] + byte);
      }
#pragma unroll
      for (int ot = 0; ot < 2; ++ot)
        cf[ot] = *(const bf16x8*)(Cb + (size_t)(o0 + ot * 16 + rl) * NST + k0 + kg * 8);
#pragma unroll
      for (int mt = 0; mt < 2; ++mt)
#pragma unroll
        for (int ot = 0; ot < 2; ++ot)
          a2[mt][ot] = __builtin_amdgcn_mfma_f32_16x16x32_bf16(af[mt], cf[ot], a2[mt][ot], 0, 0, 0);
    }
#pragma unroll
    for (int mt = 0; mt < 2; ++mt)
#pragma unroll
      for (int ot = 0; ot < 2; ++ot)
#pragma unroll
        for (int r = 0; r < 4; ++r) {
          int t = mt * 16 + kg * 4 + r;
          int o = o0 + ot * 16 + rl;
          out[(((size_t)(c * CLEN + t)) * BATCH + b) * OUTF + o] = a2[mt][ot][r];
        }
  }
}

// ---------------------------------------------------------------------------
extern "C" void kernel_launch(void* const* d_in, const int* in_sizes, int n_in,
                              void* d_out, int out_size, void* d_ws, size_t ws_size,
                              hipStream_t stream) {
  const float* x  = (const float*)d_in[0];
  const float* ll = (const float*)d_in[1];
  const float* Bm = (const float*)d_in[2];
  const float* Cm = (const float*)d_in[3];

  char* ws = (char*)d_ws;
  float* lam  = (float*)(ws);
  float* lamG = (float*)(ws + 2048);
  float* l2la = (float*)(ws + 4096);
  bf16*  Bb   = (bf16*)(ws + 6144);
  bf16*  Cb   = (bf16*)(ws + 6144 + NST * INF * 2);
  float* Z    = (float*)(ws + 6144 + NST * INF * 2 + OUTF * NST * 2);
  float* S0   = (float*)((char*)Z + (size_t)NCG * BATCH * NST * 4);
  bf16*  bfrag= (bf16*)((char*)S0 + (size_t)NCG * BATCH * NST * 4);
  const size_t NEED = ((char*)bfrag - ws) + (size_t)SEQ * BATCH * NST * 2;  // ~67MB

  float* out = (float*)d_out;
  float* fin = out + (size_t)SEQ * BATCH * OUTF;

  k_prep<<<dim3(512), dim3(256), 0, stream>>>(ll, Bm, Cm, lam, lamG, l2la, Bb, Cb);
  if (ws_size >= NEED) {
    k_pass0<1><<<dim3(NBLK), dim3(512), 0, stream>>>(x, Bb, lam, Z, bfrag);
    k_chain<<<dim3(BATCH, 4), dim3(128), 0, stream>>>(Z, lamG, S0, fin);
    k_gemm2b<<<dim3(1024), dim3(512), 0, stream>>>(bfrag, Cb, S0, l2la, out);
  } else {
    k_pass0<0><<<dim3(NBLK), dim3(512), 0, stream>>>(x, Bb, lam, Z, bfrag);
    k_chain<<<dim3(BATCH, 4), dim3(128), 0, stream>>>(Z, lamG, S0, fin);
    k_pass1_fb<<<dim3(NBLK), dim3(512), 0, stream>>>(x, Bb, Cb, lam, S0, out, fin);
  }
}